// Round 10
// baseline (366.268 us; speedup 1.0000x reference)
//
#include <hip/hip_runtime.h>
#include <cstdint>

#define BB    8
#define CIN   256
#define COUT  256
#define HH    64
#define WW    64

typedef __attribute__((ext_vector_type(8))) short    s16x8;
typedef __attribute__((ext_vector_type(8))) unsigned short u16x8;
typedef __attribute__((ext_vector_type(4))) float    f32x4;

__device__ __forceinline__ float bf2f(unsigned short u) {
    unsigned int v = ((unsigned int)u) << 16;
    return __builtin_bit_cast(float, v);
}
__device__ __forceinline__ unsigned short f2bf(float f) {
    unsigned int u = __builtin_bit_cast(unsigned int, f);
    unsigned int r = (u + 0x7FFFu + ((u >> 16) & 1u)) >> 16;   // RNE
    return (unsigned short)r;
}

// Manual grid sync: all 512 blocks are co-resident by construction
// (LDS 76032B -> exactly 2 blocks/CU; grid = 2*256). Device-scope fence +
// counter; agent-scope acquire spin.
__device__ __forceinline__ void grid_sync(int* cnt, int t) {
    __syncthreads();                   // per-thread vmem drained (vmcnt0 at barrier)
    if (t == 0) {
        __threadfence();               // release: L2 writeback on this XCD
        atomicAdd(cnt, 1);
        while (__hip_atomic_load(cnt, __ATOMIC_ACQUIRE, __HIP_MEMORY_SCOPE_AGENT) < 512) {}
        __threadfence();               // acquire: invalidate local caches
    }
    __syncthreads();
}

// ---------------------------------------------------------------------------
// Fully fused: pack -> sync -> offconv(LDS) + deform GEMM + stats -> sync ->
// BN+ReLU store. 512 blocks (one per (b,h), b=blk&7 XCD affinity), 512 thr.
// LDS union (76032 B):
//   [0,16640)     tileF fp32 transpose tile (64x65)          | phase A
//   [0,53856)     S3 offconv 3-row window (3*66*136 u16)     | B1
//   [0,67584)     S sampled-tap double buffer (2x64x264 u16) | B2
//   [0,32896)     T y-tile (64px x 257 u16)                  | epilogue/C
//   [67584,76032) OMS om tile (64x33 f32)                    | B1 write, B2 read
//   [67584,69632) sc/sh (256+256 f32)                        | phase C
__global__ __launch_bounds__(512, 4)
void k_all(const float* __restrict__ xg,
           const float* __restrict__ woffg,
           const float* __restrict__ boffg,
           const float* __restrict__ wg,
           const float* __restrict__ biasg,
           const float* __restrict__ gammag,
           const float* __restrict__ betag,
           unsigned short* __restrict__ xT,
           unsigned short* __restrict__ wTkAll,   // 8 per-XCD copies
           unsigned short* __restrict__ wofTAll,  // 8 per-XCD copies
           float* __restrict__ gsum,
           float* __restrict__ gssq,
           int* __restrict__ cnt,
           float* __restrict__ out) {
    __shared__ __align__(16) char smem[76032];
    int blk = blockIdx.x;
    int b = blk & 7, h = blk >> 3;
    int t = threadIdx.x;
    int lane = t & 63, wv = t >> 6;
    int lm = lane & 15, q = lane >> 4;
    const f32x4 FZ = {0.f, 0.f, 0.f, 0.f};

    unsigned short* wTk  = wTkAll  + (size_t)b * 589824;
    unsigned short* wofT = wofTAll + (size_t)b * 73728;

    // ============================ Phase A: packs ============================
    {
        int k = blk >> 3;              // 0..63 within this b-group
        // per-XCD weight copy: this block packs slice k (9216 elems)
        for (int r = 0; r < 18; ++r) {
            int idx = k * 9216 + r * 512 + t;
            int j   = idx & 7;
            int qq  = (idx >> 3) & 3;
            int o16 = (idx >> 5) & 15;
            int n16 = (idx >> 9) & 15;
            int kc  = (idx >> 13) & 7;
            int tp  = idx >> 16;
            int c = kc * 32 + qq * 8 + j;
            int o = n16 * 16 + o16;
            wTk[idx] = f2bf(wg[(o * 256 + c) * 9 + tp]);
        }
        // per-XCD wofT copy: slice k (1152 elems)
        for (int r = 0; r < 3; ++r) {
            int j2 = r * 512 + t;
            if (j2 < 1152) {
                int idx = k * 1152 + j2;
                int c  = idx & 255;
                int j  = (idx >> 8) & 31;
                int tp = idx >> 13;
                wofT[idx] = f2bf((j < 27) ? woffg[(j * 256 + c) * 9 + tp] : 0.f);
            }
        }
        // x pack for this (b,h): [C,W] fp32 -> xT[b,h,w,c] bf16
        float* tileF = (float*)smem;   // 64 x 65
        for (int cq = 0; cq < 4; ++cq) {
            int c0 = cq * 64;
            __syncthreads();
#pragma unroll
            for (int r = 0; r < 8; ++r) {
                int idx = t + r * 512;             // 0..4095
                int i = idx >> 6, w_ = idx & 63;
                tileF[i * 65 + w_] = xg[(((b * 256 + c0 + i) * 64 + h) * 64) + w_];
            }
            __syncthreads();
            {
                int w_ = t >> 3, c8 = (t & 7) * 8;
                u16x8 res;
#pragma unroll
                for (int kk = 0; kk < 8; ++kk) res[kk] = f2bf(tileF[(c8 + kk) * 65 + w_]);
                *reinterpret_cast<u16x8*>(&xT[((b * 64 + h) * 64 + w_) * 256 + c0 + c8]) = res;
            }
        }
    }
    grid_sync(&cnt[0], t);

    // ===================== Phase B1: offset conv -> OMS =====================
    {
        unsigned short* S3 = (unsigned short*)smem;          // [3*66*136]
        float* OMS = (float*)(smem + 67584);                 // [64*33]
        f32x4 oacc0 = FZ, oacc1 = FZ;
        int p0w = wv * 16;   // only wv<4 meaningful
        for (int cc = 0; cc < 2; ++cc) {
            __syncthreads();
            if (t < 96) {    // zero w=0 / w=65 pad columns
                int rr = t >> 5, col = (t >> 4) & 1, c8 = (t & 15) * 8;
                u16x8 z = {0,0,0,0,0,0,0,0};
                *reinterpret_cast<u16x8*>(&S3[(rr * 66 + col * 65) * 136 + c8]) = z;
            }
#pragma unroll
            for (int r = 0; r < 6; ++r) {
                int v = t + r * 512;               // over 3*64*16 vec8 units
                int rr = v >> 10, rem = v & 1023;
                int w_ = rem >> 4, c8 = (rem & 15) * 8;
                int hr = h + rr - 1;
                u16x8 d = {0,0,0,0,0,0,0,0};
                if (hr >= 0 && hr < 64)
                    d = *reinterpret_cast<const u16x8*>(xT + ((b * 64 + hr) * 64 + w_) * 256 + cc * 128 + c8);
                *reinterpret_cast<u16x8*>(&S3[(rr * 66 + w_ + 1) * 136 + c8]) = d;
            }
            __syncthreads();
            if (wv < 4) {
#pragma unroll
                for (int tp = 0; tp < 9; ++tp) {
                    int dh = tp / 3, dw = tp % 3;
                    const unsigned short* wb = wofT + (tp * 32 + lm) * 256 + cc * 128;
#pragma unroll
                    for (int kc = 0; kc < 4; ++kc) {
                        s16x8 a = *reinterpret_cast<const s16x8*>(
                            &S3[(dh * 66 + p0w + lm + dw) * 136 + kc * 32 + q * 8]);
                        s16x8 b0 = *reinterpret_cast<const s16x8*>(wb + kc * 32 + q * 8);
                        s16x8 b1 = *reinterpret_cast<const s16x8*>(wb + 16 * 256 + kc * 32 + q * 8);
                        oacc0 = __builtin_amdgcn_mfma_f32_16x16x32_bf16(a, b0, oacc0, 0, 0, 0);
                        oacc1 = __builtin_amdgcn_mfma_f32_16x16x32_bf16(a, b1, oacc1, 0, 0, 0);
                    }
                }
            }
        }
        if (wv < 4) {
#pragma unroll
            for (int n = 0; n < 2; ++n) {
                int j = n * 16 + lm;
                float bj = (j < 27) ? boffg[j] : 0.f;
                f32x4 a = n ? oacc1 : oacc0;
#pragma unroll
                for (int i = 0; i < 4; ++i)
                    OMS[(p0w + q * 4 + i) * 33 + j] = a[i] + bj;
            }
        }
        __syncthreads();   // OMS ready; S3 reads done before S writes
    }

    // ================= Phase B2: main GEMM (producer/consumer) ==============
    unsigned short* S = (unsigned short*)smem;               // [2][64*264]
    float* OMS = (float*)(smem + 67584);
    f32x4 acc[4][4];
#pragma unroll
    for (int m = 0; m < 4; ++m)
#pragma unroll
        for (int n = 0; n < 4; ++n) acc[m][n] = FZ;

    if (wv >= 4) {
        // ------------------------- producer -------------------------
        int pw = wv - 4;
        int s  = lane & 7;                 // 16B sub-chunk within 128B window
        int pA = pw * 16 + (lane >> 3);    // group A pixel (8 lanes each)
        int pB = pA + 8;                   // group B pixel
        int rb = b * 4096;

        float wgA[4], wgB[4];
        int   adA[4], adB[4];

        auto setup = [&](int tp, int p, float* wgt, int* ad) {
            float oh = OMS[p * 33 + 2 * tp];
            float ow = OMS[p * 33 + 2 * tp + 1];
            float mv = OMS[p * 33 + 18 + tp];
            float mk = 1.f / (1.f + __expf(-mv));
            float ph = (float)(h + tp / 3 - 1) + oh;
            float pw_ = (float)(p + tp % 3 - 1) + ow;
            float fh0 = floorf(ph), fw0 = floorf(pw_);
            int ih0 = (int)fh0, iw0 = (int)fw0;
            float lh = ph - fh0, lw = pw_ - fw0;
            float hh = 1.f - lh, hw_ = 1.f - lw;
            bool vh0 = (ih0 >= 0) & (ih0 < 64);
            bool vh1 = (ih0 + 1 >= 0) & (ih0 + 1 < 64);
            bool vw0 = (iw0 >= 0) & (iw0 < 64);
            bool vw1 = (iw0 + 1 >= 0) & (iw0 + 1 < 64);
            wgt[0] = hh * hw_ * mk * (float)(vh0 & vw0);
            wgt[1] = hh * lw  * mk * (float)(vh0 & vw1);
            wgt[2] = lh * hw_ * mk * (float)(vh1 & vw0);
            wgt[3] = lh * lw  * mk * (float)(vh1 & vw1);
            int ch0 = min(max(ih0, 0), 63), ch1 = min(max(ih0 + 1, 0), 63);
            int cw0 = min(max(iw0, 0), 63), cw1 = min(max(iw0 + 1, 0), 63);
            ad[0] = ((rb + ch0 * 64 + cw0) * 256);
            ad[1] = ((rb + ch0 * 64 + cw1) * 256);
            ad[2] = ((rb + ch1 * 64 + cw0) * 256);
            ad[3] = ((rb + ch1 * 64 + cw1) * 256);
        };

        u16x8 rP[4], rQ[4];
        auto issueSet = [&](const int* ad, int j, u16x8* r) {
            int off = j * 64 + s * 8;
#pragma unroll
            for (int c = 0; c < 4; ++c)
                r[c] = *reinterpret_cast<const u16x8*>(xT + ad[c] + off);
        };
        auto blendSet = [&](int buf, int p, const float* wgt, int j, u16x8* r) {
            u16x8 res;
#pragma unroll
            for (int k = 0; k < 8; ++k) {
                float v = wgt[0] * bf2f(r[0][k]);
                v = fmaf(wgt[1], bf2f(r[1][k]), v);
                v = fmaf(wgt[2], bf2f(r[2][k]), v);
                v = fmaf(wgt[3], bf2f(r[3][k]), v);
                res[k] = f2bf(v);
            }
            *reinterpret_cast<u16x8*>(&S[buf * 16896 + p * 264 + j * 64 + s * 8]) = res;
        };
        auto fillTap = [&](int tp, int buf) {
            setup(tp, pA, wgA, adA);
            setup(tp, pB, wgB, adB);
            issueSet(adA, 0, rP);
            issueSet(adA, 1, rQ);
            blendSet(buf, pA, wgA, 0, rP);  issueSet(adA, 2, rP);
            blendSet(buf, pA, wgA, 1, rQ);  issueSet(adA, 3, rQ);
            blendSet(buf, pA, wgA, 2, rP);  issueSet(adB, 0, rP);
            blendSet(buf, pA, wgA, 3, rQ);  issueSet(adB, 1, rQ);
            blendSet(buf, pB, wgB, 0, rP);  issueSet(adB, 2, rP);
            blendSet(buf, pB, wgB, 1, rQ);  issueSet(adB, 3, rQ);
            blendSet(buf, pB, wgB, 2, rP);
            blendSet(buf, pB, wgB, 3, rQ);
        };

        fillTap(0, 0);
        __syncthreads();
        for (int tp = 0; tp < 9; ++tp) {
            if (tp < 8) fillTap(tp + 1, (tp + 1) & 1);
            __syncthreads();
        }
    } else {
        // ------------------------- consumer -------------------------
        __syncthreads();               // matches producer prologue barrier
        for (int tp = 0; tp < 9; ++tp) {
            const unsigned short* Sc = &S[(tp & 1) * 16896];
            const unsigned short* wtap = wTk + (size_t)tp * 65536
                                       + (size_t)(wv * 4) * 512 + lm * 32 + q * 8;
            s16x8 wbuf[2][4];
#pragma unroll
            for (int n = 0; n < 4; ++n)
                wbuf[0][n] = *reinterpret_cast<const s16x8*>(wtap + n * 512);
#pragma unroll
            for (int kc = 0; kc < 8; ++kc) {
                if (kc < 7) {
                    const unsigned short* wb = wtap + (kc + 1) * 8192;
#pragma unroll
                    for (int n = 0; n < 4; ++n)
                        wbuf[(kc + 1) & 1][n] = *reinterpret_cast<const s16x8*>(wb + n * 512);
                }
#pragma unroll
                for (int mt = 0; mt < 4; ++mt) {
                    s16x8 a = *reinterpret_cast<const s16x8*>(
                        &Sc[(mt * 16 + lm) * 264 + kc * 32 + q * 8]);
#pragma unroll
                    for (int n = 0; n < 4; ++n)
                        acc[mt][n] = __builtin_amdgcn_mfma_f32_16x16x32_bf16(
                            a, wbuf[kc & 1][n], acc[mt][n], 0, 0, 0);
                }
            }
            __syncthreads();
        }
    }

    // ========== Epilogue: y -> LDS T (bf16) + stats atomics ==========
    __syncthreads();                   // all S reads done; T aliases S[0]
    unsigned short* T = (unsigned short*)smem;    // [64px x 257]
    if (wv < 4) {
#pragma unroll
        for (int nt = 0; nt < 4; ++nt) {
            int o = wv * 64 + nt * 16 + lm;
            float bo = biasg[o];
            float sacc = 0.f, ssacc = 0.f;
#pragma unroll
            for (int mt = 0; mt < 4; ++mt) {
#pragma unroll
                for (int i = 0; i < 4; ++i) {
                    float v = acc[mt][nt][i] + bo;
                    T[(mt * 16 + q * 4 + i) * 257 + o] = f2bf(v);
                    sacc += v; ssacc += v * v;
                }
            }
            sacc  += __shfl_xor(sacc, 16);
            sacc  += __shfl_xor(sacc, 32);
            ssacc += __shfl_xor(ssacc, 16);
            ssacc += __shfl_xor(ssacc, 32);
            if (q == 0) {
                atomicAdd(&gsum[o], sacc);
                atomicAdd(&gssq[o], ssacc);
            }
        }
    }
    grid_sync(&cnt[1], t);

    // ==================== Phase C: BN + ReLU + store ====================
    float* sc = (float*)(smem + 67584);
    float* sh = sc + 256;
    if (t < 256) {
        const float invn = 1.f / 32768.f;
        float s_  = __hip_atomic_load(&gsum[t], __ATOMIC_ACQUIRE, __HIP_MEMORY_SCOPE_AGENT);
        float ss_ = __hip_atomic_load(&gssq[t], __ATOMIC_ACQUIRE, __HIP_MEMORY_SCOPE_AGENT);
        float mean = s_ * invn;
        float var = ss_ * invn - mean * mean;
        float inv = rsqrtf(var + 1e-5f);
        float g = gammag[t] * inv;
        sc[t] = g;
        sh[t] = betag[t] - mean * g;
    }
    __syncthreads();
    float* obase = out + (size_t)b * (256 * 4096) + h * 64;
#pragma unroll
    for (int r = 0; r < 8; ++r) {
        int idx = t + r * 512;             // 0..4095
        int o = idx >> 4, w4 = (idx & 15) * 4;
        float scl = sc[o], shf = sh[o];
        float4 vo;
        vo.x = fmaxf(bf2f(T[(w4 + 0) * 257 + o]) * scl + shf, 0.f);
        vo.y = fmaxf(bf2f(T[(w4 + 1) * 257 + o]) * scl + shf, 0.f);
        vo.z = fmaxf(bf2f(T[(w4 + 2) * 257 + o]) * scl + shf, 0.f);
        vo.w = fmaxf(bf2f(T[(w4 + 3) * 257 + o]) * scl + shf, 0.f);
        *reinterpret_cast<float4*>(obase + (size_t)o * 4096 + w4) = vo;
    }
}

// ---------------------------------------------------------------------------
extern "C" void kernel_launch(void* const* d_in, const int* in_sizes, int n_in,
                              void* d_out, int out_size, void* d_ws, size_t ws_size,
                              hipStream_t stream) {
    const float* x      = (const float*)d_in[0];
    const float* w_off  = (const float*)d_in[1];
    const float* b_off  = (const float*)d_in[2];
    const float* weight = (const float*)d_in[3];
    const float* bias   = (const float*)d_in[4];
    const float* gamma  = (const float*)d_in[5];
    const float* beta   = (const float*)d_in[6];

    char* ws = (char*)d_ws;
    const size_t OFF_XT    = 0;                       // 16,777,216  bf16 xT
    const size_t OFF_WT    = OFF_XT + 16777216;       //  9,437,184  bf16 wTk x8
    const size_t OFF_WOFT  = OFF_WT + 9437184;        //  1,179,648  bf16 wofT x8
    const size_t OFF_SUM   = OFF_WOFT + 1179648;      //      1,024
    const size_t OFF_SUMSQ = OFF_SUM + 1024;          //      1,024
    const size_t OFF_CNT   = OFF_SUMSQ + 1024;        //        128

    unsigned short* xT   = (unsigned short*)(ws + OFF_XT);
    unsigned short* wTk  = (unsigned short*)(ws + OFF_WT);
    unsigned short* wofT = (unsigned short*)(ws + OFF_WOFT);
    float* gsum = (float*)(ws + OFF_SUM);
    float* gssq = (float*)(ws + OFF_SUMSQ);
    int*   cnt  = (int*)(ws + OFF_CNT);
    float* outp = (float*)d_out;

    // zero gsum + gssq + counters (re-poisoned to 0xAA before every launch)
    hipMemsetAsync(ws + OFF_SUM, 0, 2048 + 128, stream);

    k_all<<<512, 512, 0, stream>>>(x, w_off, b_off, weight, bias, gamma, beta,
                                   xT, wTk, wofT, gsum, gssq, cnt, outp);
}

// Round 11
// 200.918 us; speedup vs baseline: 1.8230x; 1.8230x over previous
//
#include <hip/hip_runtime.h>
#include <cstdint>

#define BB    8
#define CIN   256
#define COUT  256
#define HH    64
#define WW    64

typedef __attribute__((ext_vector_type(8))) short    s16x8;
typedef __attribute__((ext_vector_type(8))) unsigned short u16x8;
typedef __attribute__((ext_vector_type(4))) unsigned short u16x4;
typedef __attribute__((ext_vector_type(4))) float    f32x4;

__device__ __forceinline__ float bf2f(unsigned short u) {
    unsigned int v = ((unsigned int)u) << 16;
    return __builtin_bit_cast(float, v);
}
__device__ __forceinline__ unsigned short f2bf(float f) {   // RNE (pack kernels)
    unsigned int u = __builtin_bit_cast(unsigned int, f);
    unsigned int r = (u + 0x7FFFu + ((u >> 16) & 1u)) >> 16;
    return (unsigned short)r;
}
__device__ __forceinline__ unsigned short f2bf_rz(float f) { // truncate (hot blend)
    return (unsigned short)(__builtin_bit_cast(unsigned int, f) >> 16);
}

// ---------------------------------------------------------------------------
// 1) merged packs + stats zeroing, 4640 blocks x 256 thr:
//    blk 0..2047   : x -> xT [B,H,W,C] bf16 (b=blk&7 XCD affinity)
//    blk 2048..4351: weight -> wTk[tap][kc8][n16][o16][q4][j8] bf16
//    blk 4352..4639: w_off  -> wofT[tap][j32][c] bf16
__global__ void k_pack(const float* __restrict__ x,
                       const float* __restrict__ w,
                       const float* __restrict__ woff,
                       unsigned short* __restrict__ xT,
                       unsigned short* __restrict__ wTk,
                       unsigned short* __restrict__ wofT,
                       float* __restrict__ gsum,
                       float* __restrict__ gssq) {
    int blk = blockIdx.x;
    int t = threadIdx.x;
    __shared__ float tile[64 * 65];
    if (blk == 0 && t < 256) { gsum[t] = 0.f; gssq[t] = 0.f; }
    if (blk < 2048) {
        int b    = blk & 7;
        int rest = blk >> 3;
        int h    = rest >> 2;
        int c0   = (rest & 3) * 64;
#pragma unroll
        for (int r = 0; r < 16; ++r) {
            int idx = t + r * 256;
            int i = idx >> 6, w_ = idx & 63;
            tile[i * 65 + w_] = x[(((b * 256 + c0 + i) * 64 + h) * 64) + w_];
        }
        __syncthreads();
#pragma unroll
        for (int r = 0; r < 2; ++r) {
            int idx = t + r * 256;          // 0..511 = (w, c8)
            int w_ = idx >> 3;
            int c8 = (idx & 7) * 8;
            u16x8 res;
#pragma unroll
            for (int k = 0; k < 8; ++k) res[k] = f2bf(tile[(c8 + k) * 65 + w_]);
            *reinterpret_cast<u16x8*>(&xT[((b * 64 + h) * 64 + w_) * 256 + c0 + c8]) = res;
        }
    } else if (blk < 4352) {
        int idx = (blk - 2048) * 256 + t;   // 0..589,823
        int j   = idx & 7;
        int q   = (idx >> 3) & 3;
        int o16 = (idx >> 5) & 15;
        int n16 = (idx >> 9) & 15;
        int kc  = (idx >> 13) & 7;
        int tp  = idx >> 16;
        int c = kc * 32 + q * 8 + j;
        int o = n16 * 16 + o16;
        wTk[idx] = f2bf(w[(o * 256 + c) * 9 + tp]);
    } else {
        int idx = (blk - 4352) * 256 + t;   // 0..73,727
        int c  = idx & 255;
        int j  = (idx >> 8) & 31;
        int tp = idx >> 13;
        wofT[idx] = f2bf((j < 27) ? woff[(j * 256 + c) * 9 + tp] : 0.f);
    }
}

// ---------------------------------------------------------------------------
// 2) main kernel: offconv (B1, 8-wave kc-split + B prefetch, om in LDS)
//    + deform GEMM (B2, producer/consumer) + epilogue (y16 + stats).
// 512 blocks (one per (b,h), b=blk&7 XCD affinity), 512 thr = 8 waves.
// LDS union (76032 B):
//   [0,53856)     S3 offconv 3-row window (3*66*136 u16)     | B1
//   [53856,62304) PART offconv partial sums (64x33 f32)      | B1
//   [0,67584)     S sampled-tap double buffer (2x64x264 u16) | B2
//   [67584,76032) OMS om tile (64x33 f32)                    | B1 write, B2 read
__global__ __launch_bounds__(512, 4)
void k_main(const unsigned short* __restrict__ xT,
            const unsigned short* __restrict__ wTk,
            const unsigned short* __restrict__ wofT,
            const float* __restrict__ boffg,
            const float* __restrict__ bias,
            unsigned short* __restrict__ y16,
            float* __restrict__ gsum, float* __restrict__ gssq) {
    __shared__ __align__(16) char smem[76032];
    int blk = blockIdx.x;
    int b = blk & 7, h = blk >> 3;
    int pblk = b * 64 + h;
    int t = threadIdx.x;
    int lane = t & 63, wv = t >> 6;
    int lm = lane & 15, q = lane >> 4;
    const f32x4 FZ = {0.f, 0.f, 0.f, 0.f};

    // ===== Phase B1: offset conv -> OMS (8-wave kc-split, B prefetch) =====
    {
        unsigned short* S3 = (unsigned short*)smem;          // [3*66*136]
        float* PART = (float*)(smem + 53856);                // [64*33]
        float* OMS  = (float*)(smem + 67584);                // [64*33]
        f32x4 oacc0 = FZ, oacc1 = FZ;
        int myTile = wv & 3;            // px tile (16 px)
        int myKH   = wv >> 2;           // kc half: kc in {2*myKH, 2*myKH+1}
        int p0w = myTile * 16;
        for (int cc = 0; cc < 2; ++cc) {
            __syncthreads();
            if (t < 96) {    // zero w=0 / w=65 pad columns
                int rr = t >> 5, col = (t >> 4) & 1, c8 = (t & 15) * 8;
                u16x8 z = {0,0,0,0,0,0,0,0};
                *reinterpret_cast<u16x8*>(&S3[(rr * 66 + col * 65) * 136 + c8]) = z;
            }
#pragma unroll
            for (int r = 0; r < 6; ++r) {
                int v = t + r * 512;               // over 3*64*16 vec8 units
                int rr = v >> 10, rem = v & 1023;
                int w_ = rem >> 4, c8 = (rem & 15) * 8;
                int hr = h + rr - 1;
                u16x8 d = {0,0,0,0,0,0,0,0};
                if (hr >= 0 && hr < 64)
                    d = *reinterpret_cast<const u16x8*>(xT + ((b * 64 + hr) * 64 + w_) * 256 + cc * 128 + c8);
                *reinterpret_cast<u16x8*>(&S3[(rr * 66 + w_ + 1) * 136 + c8]) = d;
            }
            __syncthreads();
            // all 8 waves MFMA, each covering 2 kc (64 c) of this cc-half,
            // with tap-ahead B prefetch.
            {
                int boff = cc * 128 + myKH * 64 + q * 8;
                s16x8 pb[4], nb[4];
                {
                    const unsigned short* wb = wofT + (0 * 32 + lm) * 256 + boff;
                    pb[0] = *reinterpret_cast<const s16x8*>(wb);
                    pb[1] = *reinterpret_cast<const s16x8*>(wb + 32);
                    pb[2] = *reinterpret_cast<const s16x8*>(wb + 16 * 256);
                    pb[3] = *reinterpret_cast<const s16x8*>(wb + 16 * 256 + 32);
                }
#pragma unroll
                for (int tp = 0; tp < 9; ++tp) {
                    if (tp < 8) {
                        const unsigned short* wb = wofT + ((tp + 1) * 32 + lm) * 256 + boff;
                        nb[0] = *reinterpret_cast<const s16x8*>(wb);
                        nb[1] = *reinterpret_cast<const s16x8*>(wb + 32);
                        nb[2] = *reinterpret_cast<const s16x8*>(wb + 16 * 256);
                        nb[3] = *reinterpret_cast<const s16x8*>(wb + 16 * 256 + 32);
                    }
                    int dh = tp / 3, dw_ = tp % 3;
                    int arow = (dh * 66 + p0w + lm + dw_) * 136 + myKH * 64 + q * 8;
                    s16x8 a0 = *reinterpret_cast<const s16x8*>(&S3[arow]);
                    s16x8 a1 = *reinterpret_cast<const s16x8*>(&S3[arow + 32]);
                    oacc0 = __builtin_amdgcn_mfma_f32_16x16x32_bf16(a0, pb[0], oacc0, 0, 0, 0);
                    oacc0 = __builtin_amdgcn_mfma_f32_16x16x32_bf16(a1, pb[1], oacc0, 0, 0, 0);
                    oacc1 = __builtin_amdgcn_mfma_f32_16x16x32_bf16(a0, pb[2], oacc1, 0, 0, 0);
                    oacc1 = __builtin_amdgcn_mfma_f32_16x16x32_bf16(a1, pb[3], oacc1, 0, 0, 0);
#pragma unroll
                    for (int i = 0; i < 4; ++i) pb[i] = nb[i];
                }
            }
        }
        __syncthreads();
        if (wv >= 4) {                  // upper kc-half writes partials
#pragma unroll
            for (int i = 0; i < 4; ++i) {
                int prow = p0w + q * 4 + i;
                PART[prow * 33 + lm]      = oacc0[i];
                PART[prow * 33 + 16 + lm] = oacc1[i];
            }
        }
        __syncthreads();
        if (wv < 4) {                   // lower half combines + bias -> OMS
#pragma unroll
            for (int n = 0; n < 2; ++n) {
                int j = n * 16 + lm;
                float bj = (j < 27) ? boffg[j] : 0.f;
                f32x4 a = n ? oacc1 : oacc0;
#pragma unroll
                for (int i = 0; i < 4; ++i) {
                    int prow = p0w + q * 4 + i;
                    OMS[prow * 33 + j] = a[i] + PART[prow * 33 + j] + bj;
                }
            }
        }
        __syncthreads();   // OMS ready; S3/PART reads done before S writes
    }

    // ================= Phase B2: main GEMM (producer/consumer) ==============
    unsigned short* S = (unsigned short*)smem;               // [2][64*264]
    float* OMS = (float*)(smem + 67584);
    f32x4 acc[4][4];
#pragma unroll
    for (int m = 0; m < 4; ++m)
#pragma unroll
        for (int n = 0; n < 4; ++n) acc[m][n] = FZ;

    if (wv >= 4) {
        // ------------------------- producer -------------------------
        int pw = wv - 4;
        int s  = lane & 7;                 // 16B sub-chunk within 128B window
        int pA = pw * 16 + (lane >> 3);    // group A pixel (8 lanes each)
        int pB = pA + 8;                   // group B pixel
        int rb = b * 4096;

        float wgA[4], wgB[4];
        int   adA[4], adB[4];

        auto setup = [&](int tp, int p, float* wgt, int* ad) {
            float oh = OMS[p * 33 + 2 * tp];
            float ow = OMS[p * 33 + 2 * tp + 1];
            float mv = OMS[p * 33 + 18 + tp];
            float mk = 1.f / (1.f + __expf(-mv));
            float ph = (float)(h + tp / 3 - 1) + oh;
            float pw_ = (float)(p + tp % 3 - 1) + ow;
            float fh0 = floorf(ph), fw0 = floorf(pw_);
            int ih0 = (int)fh0, iw0 = (int)fw0;
            float lh = ph - fh0, lw = pw_ - fw0;
            float hh = 1.f - lh, hw_ = 1.f - lw;
            bool vh0 = (ih0 >= 0) & (ih0 < 64);
            bool vh1 = (ih0 + 1 >= 0) & (ih0 + 1 < 64);
            bool vw0 = (iw0 >= 0) & (iw0 < 64);
            bool vw1 = (iw0 + 1 >= 0) & (iw0 + 1 < 64);
            wgt[0] = hh * hw_ * mk * (float)(vh0 & vw0);
            wgt[1] = hh * lw  * mk * (float)(vh0 & vw1);
            wgt[2] = lh * hw_ * mk * (float)(vh1 & vw0);
            wgt[3] = lh * lw  * mk * (float)(vh1 & vw1);
            int ch0 = min(max(ih0, 0), 63), ch1 = min(max(ih0 + 1, 0), 63);
            int cw0 = min(max(iw0, 0), 63), cw1 = min(max(iw0 + 1, 0), 63);
            ad[0] = ((rb + ch0 * 64 + cw0) * 256);
            ad[1] = ((rb + ch0 * 64 + cw1) * 256);
            ad[2] = ((rb + ch1 * 64 + cw0) * 256);
            ad[3] = ((rb + ch1 * 64 + cw1) * 256);
        };

        u16x8 rP[4], rQ[4];
        auto issueSet = [&](const int* ad, int j, u16x8* r) {
            int off = j * 64 + s * 8;
#pragma unroll
            for (int c = 0; c < 4; ++c)
                r[c] = *reinterpret_cast<const u16x8*>(xT + ad[c] + off);
        };
        auto blendSet = [&](int buf, int p, const float* wgt, int j, u16x8* r) {
            u16x8 res;
#pragma unroll
            for (int k = 0; k < 8; ++k) {
                float v = wgt[0] * bf2f(r[0][k]);
                v = fmaf(wgt[1], bf2f(r[1][k]), v);
                v = fmaf(wgt[2], bf2f(r[2][k]), v);
                v = fmaf(wgt[3], bf2f(r[3][k]), v);
                res[k] = f2bf_rz(v);
            }
            *reinterpret_cast<u16x8*>(&S[buf * 16896 + p * 264 + j * 64 + s * 8]) = res;
        };
        auto fillTap = [&](int tp, int buf) {
            setup(tp, pA, wgA, adA);
            setup(tp, pB, wgB, adB);
            issueSet(adA, 0, rP);
            issueSet(adA, 1, rQ);
            blendSet(buf, pA, wgA, 0, rP);  issueSet(adA, 2, rP);
            blendSet(buf, pA, wgA, 1, rQ);  issueSet(adA, 3, rQ);
            blendSet(buf, pA, wgA, 2, rP);  issueSet(adB, 0, rP);
            blendSet(buf, pA, wgA, 3, rQ);  issueSet(adB, 1, rQ);
            blendSet(buf, pB, wgB, 0, rP);  issueSet(adB, 2, rP);
            blendSet(buf, pB, wgB, 1, rQ);  issueSet(adB, 3, rQ);
            blendSet(buf, pB, wgB, 2, rP);
            blendSet(buf, pB, wgB, 3, rQ);
        };

        fillTap(0, 0);
        __syncthreads();
        for (int tp = 0; tp < 9; ++tp) {
            if (tp < 8) fillTap(tp + 1, (tp + 1) & 1);
            __syncthreads();
        }
    } else {
        // ------------------------- consumer -------------------------
        __syncthreads();               // matches producer prologue barrier
        for (int tp = 0; tp < 9; ++tp) {
            const unsigned short* Sc = &S[(tp & 1) * 16896];
            const unsigned short* wtap = wTk + (size_t)tp * 65536
                                       + (size_t)(wv * 4) * 512 + lm * 32 + q * 8;
            s16x8 wbuf[2][4];
#pragma unroll
            for (int n = 0; n < 4; ++n)
                wbuf[0][n] = *reinterpret_cast<const s16x8*>(wtap + n * 512);
#pragma unroll
            for (int kc = 0; kc < 8; ++kc) {
                if (kc < 7) {
                    const unsigned short* wb = wtap + (kc + 1) * 8192;
#pragma unroll
                    for (int n = 0; n < 4; ++n)
                        wbuf[(kc + 1) & 1][n] = *reinterpret_cast<const s16x8*>(wb + n * 512);
                }
#pragma unroll
                for (int mt = 0; mt < 4; ++mt) {
                    s16x8 a = *reinterpret_cast<const s16x8*>(
                        &Sc[(mt * 16 + lm) * 264 + kc * 32 + q * 8]);
#pragma unroll
                    for (int n = 0; n < 4; ++n)
                        acc[mt][n] = __builtin_amdgcn_mfma_f32_16x16x32_bf16(
                            a, wbuf[kc & 1][n], acc[mt][n], 0, 0, 0);
                }
            }
            __syncthreads();
        }
    }

    // ====== epilogue: y16 (bf16, tile layout) + stats (consumers only) ======
    if (wv < 4) {
        u16x4* yv = reinterpret_cast<u16x4*>(y16);
#pragma unroll
        for (int nt = 0; nt < 4; ++nt) {
            int o = wv * 64 + nt * 16 + lm;
            float bo = bias[o];
            float sacc = 0.f, ssacc = 0.f;
#pragma unroll
            for (int mt = 0; mt < 4; ++mt) {
                u16x4 st;
#pragma unroll
                for (int i = 0; i < 4; ++i) {
                    float v = acc[mt][nt][i] + bo;
                    st[i] = f2bf(v);
                    sacc += v; ssacc += v * v;
                }
                int idx4 = ((pblk * 4 + wv) * 16 + nt * 4 + mt) * 64 + lane;
                yv[idx4] = st;
            }
            sacc  += __shfl_xor(sacc, 16);
            sacc  += __shfl_xor(sacc, 32);
            ssacc += __shfl_xor(ssacc, 16);
            ssacc += __shfl_xor(ssacc, 32);
            if (q == 0) {
                atomicAdd(&gsum[o], sacc);
                atomicAdd(&gssq[o], ssacc);
            }
        }
    }
}

// ---------------------------------------------------------------------------
// 3) BN + ReLU + untile + transpose; float4 stores (16B/lane)
__global__ void k_bnrelu(const unsigned short* __restrict__ y16,
                         const float* __restrict__ gsum, const float* __restrict__ gssq,
                         const float* __restrict__ gamma, const float* __restrict__ beta,
                         float* __restrict__ out) {
    int blk = blockIdx.x;
    int b = blk & 7, h = blk >> 3;
    int pblk = b * 64 + h;
    __shared__ unsigned short T[64 * 257];
    __shared__ float sc[256], sh[256];
    int t = threadIdx.x;
    {
        const float n = 32768.f;
        float mean = gsum[t] / n;
        float var = gssq[t] / n - mean * mean;
        float inv = rsqrtf(var + 1e-5f);
        float s = gamma[t] * inv;
        sc[t] = s;
        sh[t] = beta[t] - mean * s;
    }
    const u16x4* yv = reinterpret_cast<const u16x4*>(y16) + pblk * 4096;
#pragma unroll
    for (int r = 0; r < 16; ++r) {
        int v = t + r * 256;
        u16x4 d = yv[v];
        int lane = v & 63, mt = (v >> 6) & 3, nt = (v >> 8) & 3, wvv = (v >> 10) & 3;
        int p = mt * 16 + (lane >> 4) * 4;
        int o = wvv * 64 + nt * 16 + (lane & 15);
        T[(p + 0) * 257 + o] = d[0];
        T[(p + 1) * 257 + o] = d[1];
        T[(p + 2) * 257 + o] = d[2];
        T[(p + 3) * 257 + o] = d[3];
    }
    __syncthreads();
    int w4   = (t & 15) * 4;
    int orow = t >> 4;
    float* obase = out + (size_t)b * (256 * 4096) + h * 64;
#pragma unroll
    for (int it = 0; it < 16; ++it) {
        int o = orow + it * 16;
        float scl = sc[o], shf = sh[o];
        float4 vo;
        vo.x = fmaxf(bf2f(T[(w4 + 0) * 257 + o]) * scl + shf, 0.f);
        vo.y = fmaxf(bf2f(T[(w4 + 1) * 257 + o]) * scl + shf, 0.f);
        vo.z = fmaxf(bf2f(T[(w4 + 2) * 257 + o]) * scl + shf, 0.f);
        vo.w = fmaxf(bf2f(T[(w4 + 3) * 257 + o]) * scl + shf, 0.f);
        *reinterpret_cast<float4*>(obase + (size_t)o * 4096 + w4) = vo;
    }
}

// ---------------------------------------------------------------------------
extern "C" void kernel_launch(void* const* d_in, const int* in_sizes, int n_in,
                              void* d_out, int out_size, void* d_ws, size_t ws_size,
                              hipStream_t stream) {
    const float* x      = (const float*)d_in[0];
    const float* w_off  = (const float*)d_in[1];
    const float* b_off  = (const float*)d_in[2];
    const float* weight = (const float*)d_in[3];
    const float* bias   = (const float*)d_in[4];
    const float* gamma  = (const float*)d_in[5];
    const float* beta   = (const float*)d_in[6];

    char* ws = (char*)d_ws;
    const size_t OFF_XT    = 0;                       // 16,777,216  bf16 xT
    const size_t OFF_WT    = OFF_XT + 16777216;       //  1,179,648  bf16 wTk
    const size_t OFF_WOFT  = OFF_WT + 1179648;        //    147,456  bf16 wofT
    const size_t OFF_Y16   = OFF_WOFT + 147456;       // 16,777,216  bf16 y tile-layout
    const size_t OFF_SUM   = OFF_Y16 + 16777216;      //      1,024
    const size_t OFF_SUMSQ = OFF_SUM + 1024;          //      1,024

    unsigned short* xT   = (unsigned short*)(ws + OFF_XT);
    unsigned short* wTk  = (unsigned short*)(ws + OFF_WT);
    unsigned short* wofT = (unsigned short*)(ws + OFF_WOFT);
    unsigned short* y16  = (unsigned short*)(ws + OFF_Y16);
    float* gsum  = (float*)(ws + OFF_SUM);
    float* gssq  = (float*)(ws + OFF_SUMSQ);

    k_pack  <<<4640, 256, 0, stream>>>(x, weight, w_off, xT, wTk, wofT, gsum, gssq);
    k_main  <<< 512, 512, 0, stream>>>(xT, wTk, wofT, b_off, bias, y16, gsum, gssq);
    k_bnrelu<<< 512, 256, 0, stream>>>(y16, gsum, gssq, gamma, beta, (float*)d_out);
}